// Round 1
// baseline (1019.089 us; speedup 1.0000x reference)
//
#include <hip/hip_runtime.h>

typedef float  f32x4  __attribute__((ext_vector_type(4)));
typedef short  bf16x8 __attribute__((ext_vector_type(8)));
typedef unsigned int   u32;
typedef unsigned short u16;

#define N_NODES 30000
#define VOCABSZ 10000
#define LOG2E 1.442695040888963f

__device__ __forceinline__ float sigm(float x){
  return __builtin_amdgcn_rcpf(1.f + __builtin_amdgcn_exp2f(-LOG2E*x));
}
__device__ __forceinline__ float tanh_(float x){
  return 1.f - 2.f*__builtin_amdgcn_rcpf(1.f + __builtin_amdgcn_exp2f((2.f*LOG2E)*x));
}
__device__ __forceinline__ u16 f2bf(float f){   // round-to-nearest-even bf16
  u32 u = __builtin_bit_cast(u32, f);
  u = u + 0x7fffu + ((u>>16)&1u);
  return (u16)(u>>16);
}
__device__ __forceinline__ float bflo(u32 u){ return __builtin_bit_cast(float, u<<16); }
__device__ __forceinline__ float bfhi(u32 u){ return __builtin_bit_cast(float, u & 0xffff0000u); }

// ---------------------------------------------------------------------------
// W_r = sum_b wcomp[r,b] * basis[b]  -> stored TRANSPOSED as [r][o][i] f32
// ---------------------------------------------------------------------------
__global__ __launch_bounds__(256) void wmat_kernel(
    const float* __restrict__ b0, const float* __restrict__ c0,
    const float* __restrict__ b1, const float* __restrict__ c1,
    const float* __restrict__ b2, const float* __restrict__ c2,
    float* __restrict__ W0, float* __restrict__ W1, float* __restrict__ W2)
{
  int id = blockIdx.x*256 + threadIdx.x;
  if (id < 32768){
    int r = id>>12, o = (id>>6)&63, i = id&63;
    float s = 0.f;
    #pragma unroll
    for (int b=0;b<4;++b) s += c0[r*4+b]*b0[b*4096 + i*64 + o];
    W0[id] = s;
  } else if (id < 65536){
    int k = id - 32768;
    int r = k>>12, o = (k>>6)&63, i = k&63;
    float s = 0.f;
    #pragma unroll
    for (int b=0;b<4;++b) s += c1[r*4+b]*b1[b*4096 + i*64 + o];
    W1[k] = s;
  } else if (id < 73728){
    int k = id - 65536;
    int r = k>>10, o = (k>>6)&15, i = k&63;
    float s = 0.f;
    #pragma unroll
    for (int b=0;b<4;++b) s += c2[r*4+b]*b2[b*1024 + i*16 + o];
    W2[k] = s;
  }
}

// ---------------------------------------------------------------------------
// emb_proj[v][j] = emb[v]@w_ih[j] + b_ih[j] + b_hh[j]   (bf16, linear [v][512])
// block = 256 thr, 64 vocab rows; j-chunks of 32 staged in LDS
// ---------------------------------------------------------------------------
__global__ __launch_bounds__(256) void embproj_kernel(
    const float* __restrict__ emb, const float* __restrict__ w_ih,
    const float* __restrict__ b_ih, const float* __restrict__ b_hh,
    u16* __restrict__ eproj)
{
  __shared__ float et[64*132];
  __shared__ float wt[32*132];
  const int tid = threadIdx.x;
  const int v0 = blockIdx.x*64;
  const int vq = tid>>4, jq = tid&15;

  for (int idx = tid*4; idx < 64*128; idx += 1024){
    int row = idx>>7, col = idx&127;
    int vr = v0 + row; if (vr > VOCABSZ-1) vr = VOCABSZ-1;
    *(f32x4*)&et[row*132+col] = *(const f32x4*)&emb[vr*128+col];
  }
  for (int jt=0; jt<16; ++jt){
    __syncthreads();
    for (int idx = tid*4; idx < 32*128; idx += 1024){
      int row = idx>>7, col = idx&127;
      *(f32x4*)&wt[row*132+col] = *(const f32x4*)&w_ih[(jt*32+row)*128+col];
    }
    __syncthreads();
    float acc[4][2] = {};
    #pragma unroll 4
    for (int k=0;k<128;++k){
      float w0v = wt[(jq*2+0)*132+k];
      float w1v = wt[(jq*2+1)*132+k];
      #pragma unroll
      for (int a=0;a<4;++a){
        float e = et[(vq*4+a)*132+k];
        acc[a][0] += e*w0v;
        acc[a][1] += e*w1v;
      }
    }
    int jb = jt*32 + jq*2;
    float bi0 = b_ih[jb]   + b_hh[jb];
    float bi1 = b_ih[jb+1] + b_hh[jb+1];
    #pragma unroll
    for (int a=0;a<4;++a){
      int v = v0 + vq*4 + a;
      if (v < VOCABSZ){
        u32 pk = (u32)f2bf(acc[a][0]+bi0) | ((u32)f2bf(acc[a][1]+bi1) << 16);
        *(u32*)&eproj[v*512 + jb] = pk;
      }
    }
  }
}

// ---------------------------------------------------------------------------
// Fused 32-step reverse LSTM + fc epilogue.
// block = 512 thr (8 waves) owns 128 nodes. Wave w owns k-slice [16w,16w+16)
// of all 4 gates; w_hh stripes live in registers (A-frags), h (bf16,
// XOR-swizzled, double-buffered 64KB LDS) is the streamed B operand.
// Z^T = W_hh * H^T via mfma_f32_16x16x32_bf16; gates_x gathered into acc.
// ---------------------------------------------------------------------------
__global__ __launch_bounds__(512, 2) void lstm_kernel(
    const int* __restrict__ tok, const u16* __restrict__ eproj,
    const float* __restrict__ w_hh, const float* __restrict__ fc_w,
    const float* __restrict__ fc_b, float* __restrict__ feats)
{
  __shared__ __align__(16) char lds[65536];
  const int tid = threadIdx.x;
  const int wave = tid>>6, lane = tid&63;
  const int c16 = lane&15, g4 = lane>>4;
  const int nb = blockIdx.x*128;

  // persistent w_hh A-fragments: j = g*128 + wave*16 + c16 ; k = kk*32+8*g4+i
  bf16x8 afr[4][4];
  #pragma unroll
  for (int g=0; g<4; ++g){
    const float* wr = w_hh + (g*128 + wave*16 + c16)*128 + g4*8;
    #pragma unroll
    for (int kk=0; kk<4; ++kk){
      f32x4 wa = *(const f32x4*)(wr + kk*32);
      f32x4 wbv = *(const f32x4*)(wr + kk*32 + 4);
      bf16x8 a;
      a[0]=(short)f2bf(wa[0]); a[1]=(short)f2bf(wa[1]);
      a[2]=(short)f2bf(wa[2]); a[3]=(short)f2bf(wa[3]);
      a[4]=(short)f2bf(wbv[0]); a[5]=(short)f2bf(wbv[1]);
      a[6]=(short)f2bf(wbv[2]); a[7]=(short)f2bf(wbv[3]);
      afr[g][kk] = a;
    }
  }
  { // zero h buffer 0
    f32x4 z = {0.f,0.f,0.f,0.f};
    for (int i = tid*16; i < 32768; i += 8192) *(f32x4*)(lds + i) = z;
  }
  const int swz = (c16&7)<<4;
  int rb[4], wb_[4];
  #pragma unroll
  for (int kk=0;kk<4;++kk) rb[kk] = c16*256 + ((kk*64 + g4*16)^swz);
  #pragma unroll
  for (int q=0;q<4;++q)  wb_[q] = c16*256 + ((wave*32 + g4*8 + q*2)^swz);

  float creg[8][4];
  #pragma unroll
  for (int nt=0;nt<8;++nt)
    #pragma unroll
    for (int q=0;q<4;++q) creg[nt][q]=0.f;

  int tokc[8], tokn[8];
  #pragma unroll
  for (int nt=0;nt<8;++nt){
    int node = nb + nt*16 + c16; if (node > N_NODES-1) node = N_NODES-1;
    tokc[nt] = tok[node*32 + 31];           // reversed time: step 0 uses t'=31
  }
  __syncthreads();

  for (int t=0; t<32; ++t){
    const int bufR = (t&1)<<15, bufW = bufR ^ 32768;
    if (t < 31){
      #pragma unroll
      for (int nt=0;nt<8;++nt){
        int node = nb + nt*16 + c16; if (node > N_NODES-1) node = N_NODES-1;
        tokn[nt] = tok[node*32 + (30 - t)];
      }
    }
    uint2 gx[2][4];
    #pragma unroll
    for (int p=0;p<2;++p){
      const u16* ep = eproj + tokc[p]*512 + wave*16 + g4*4;
      #pragma unroll
      for (int g=0; g<4; ++g) gx[p][g] = *(const uint2*)(ep + g*128);
    }
    #pragma unroll
    for (int nt=0; nt<8; ++nt){
      f32x4 acc[4];
      #pragma unroll
      for (int g=0; g<4; ++g){        // acc init = gathered gates_x
        uint2 d = gx[nt&1][g];
        acc[g][0]=bflo(d.x); acc[g][1]=bfhi(d.x);
        acc[g][2]=bflo(d.y); acc[g][3]=bfhi(d.y);
      }
      if (nt < 6){                    // prefetch gathers 2 tiles ahead
        const u16* ep = eproj + tokc[nt+2]*512 + wave*16 + g4*4;
        #pragma unroll
        for (int g=0; g<4; ++g) gx[nt&1][g] = *(const uint2*)(ep + g*128);
      }
      bf16x8 bfr[4];
      #pragma unroll
      for (int kk=0;kk<4;++kk)
        bfr[kk] = *(const bf16x8*)(lds + bufR + rb[kk] + nt*4096);
      #pragma unroll
      for (int kk=0;kk<4;++kk){
        acc[0] = __builtin_amdgcn_mfma_f32_16x16x32_bf16(afr[0][kk], bfr[kk], acc[0], 0,0,0);
        acc[1] = __builtin_amdgcn_mfma_f32_16x16x32_bf16(afr[1][kk], bfr[kk], acc[1], 0,0,0);
        acc[2] = __builtin_amdgcn_mfma_f32_16x16x32_bf16(afr[2][kk], bfr[kk], acc[2], 0,0,0);
        acc[3] = __builtin_amdgcn_mfma_f32_16x16x32_bf16(afr[3][kk], bfr[kk], acc[3], 0,0,0);
      }
      #pragma unroll
      for (int q=0;q<4;++q){          // gates: i,f,g,o
        float zi=acc[0][q], zf=acc[1][q], zg=acc[2][q], zo=acc[3][q];
        float cn = sigm(zf)*creg[nt][q] + sigm(zi)*tanh_(zg);
        creg[nt][q] = cn;
        float hn = sigm(zo)*tanh_(cn);
        *(u16*)(lds + bufW + wb_[q] + nt*4096) = f2bf(hn);
      }
    }
    #pragma unroll
    for (int nt=0;nt<8;++nt) tokc[nt] = tokn[nt];
    __syncthreads();
  }
  // fc epilogue: final h is in buffer 0; wave handles node-tile nt == wave
  f32x4 fca[4];
  #pragma unroll
  for (int ot=0;ot<4;++ot){ fca[ot][0]=0.f; fca[ot][1]=0.f; fca[ot][2]=0.f; fca[ot][3]=0.f; }
  #pragma unroll
  for (int kk=0;kk<4;++kk){
    bf16x8 b = *(const bf16x8*)(lds + rb[kk] + wave*4096);
    #pragma unroll
    for (int ot=0;ot<4;++ot){
      const float* fr = fc_w + (ot*16 + c16)*128 + kk*32 + g4*8;
      f32x4 wa = *(const f32x4*)fr;
      f32x4 wbv = *(const f32x4*)(fr+4);
      bf16x8 a;
      a[0]=(short)f2bf(wa[0]); a[1]=(short)f2bf(wa[1]);
      a[2]=(short)f2bf(wa[2]); a[3]=(short)f2bf(wa[3]);
      a[4]=(short)f2bf(wbv[0]); a[5]=(short)f2bf(wbv[1]);
      a[6]=(short)f2bf(wbv[2]); a[7]=(short)f2bf(wbv[3]);
      fca[ot] = __builtin_amdgcn_mfma_f32_16x16x32_bf16(a, b, fca[ot], 0,0,0);
    }
  }
  const int node = nb + wave*16 + c16;
  if (node < N_NODES){
    #pragma unroll
    for (int ot=0;ot<4;++ot)
      #pragma unroll
      for (int q=0;q<4;++q){
        int o = ot*16 + g4*4 + q;
        feats[node*64 + o] = fca[ot][q] + fc_b[o];
      }
  }
}

// ---------------------------------------------------------------------------
// RGCN layer: out[dst] += (relu?(h[src]))*norm @ W[rel]   (f32, atomics)
// block = 1024 thr (16 waves), wave per edge, W (f32, XOR-swizzled) in LDS.
// ---------------------------------------------------------------------------
__global__ __launch_bounds__(1024) void rgcn_kernel(
    const float* __restrict__ hsrc, const int* __restrict__ src,
    const int* __restrict__ dst, const int* __restrict__ rel,
    const float* __restrict__ enorm, const float* __restrict__ Wt,
    float* __restrict__ out, int n_edges, int NO, int relu_src)
{
  extern __shared__ __align__(16) char dlds[];
  char*  ldsW = dlds;
  float* msgb = (float*)(dlds + 8*NO*256);
  const int tid = threadIdx.x;
  const int wave = tid>>6, lane = tid&63;

  const int welems = 8*NO*64;
  for (int idx = tid; idx < welems; idx += 1024){
    int ro = idx>>6, i = idx&63;
    int o = ro % NO;
    *(float*)(ldsW + ro*256 + ((i*4) ^ ((o&7)<<4))) = Wt[idx];
  }
  __syncthreads();

  const int oo = (lane < NO) ? lane : 0;
  const int nwav = gridDim.x*16;
  int e = blockIdx.x*16 + wave;
  if (e < n_edges){
    int s0=src[e], d0=dst[e], r0=rel[e]; float nm0=enorm[e];
    float hv0 = hsrc[s0*64 + lane];
    int p = 0;
    while (true){
      int e1 = e + nwav;
      bool more = (e1 < n_edges);
      int s1=0,d1=0,r1=0; float nm1=0.f, hv1=0.f;
      if (more){
        s1=src[e1]; d1=dst[e1]; r1=rel[e1]; nm1=enorm[e1];
        hv1 = hsrc[s1*64+lane];
      }
      float m = relu_src ? fmaxf(hv0, 0.f) : hv0;
      m *= nm0;
      float* msl = msgb + (wave*2 + p)*64;
      msl[lane] = m;
      __asm__ __volatile__("s_waitcnt lgkmcnt(0)" ::: "memory");
      float a = 0.f;
      const char* wrow = ldsW + (r0*NO + oo)*256;
      const char* mrow = (const char*)msl;
      #pragma unroll
      for (int i4=0; i4<16; ++i4){
        f32x4 mv = *(const f32x4*)(mrow + i4*16);
        f32x4 wv = *(const f32x4*)(wrow + ((i4*16) ^ ((oo&7)<<4)));
        a += mv[0]*wv[0]; a += mv[1]*wv[1]; a += mv[2]*wv[2]; a += mv[3]*wv[3];
      }
      if (lane < NO) unsafeAtomicAdd(out + d0*NO + oo, a);
      if (!more) break;
      s0=s1; d0=d1; r0=r1; nm0=nm1; hv0=hv1;
      e = e1; p ^= 1;
    }
  }
}

// ---------------------------------------------------------------------------
extern "C" void kernel_launch(void* const* d_in, const int* in_sizes, int n_in,
                              void* d_out, int out_size, void* d_ws, size_t ws_size,
                              hipStream_t stream)
{
  const int*   tok    = (const int*)  d_in[0];
  const int*   src    = (const int*)  d_in[2];
  const int*   dst    = (const int*)  d_in[3];
  const int*   rel    = (const int*)  d_in[4];
  const float* enorm  = (const float*)d_in[5];
  const float* emb    = (const float*)d_in[6];
  const float* w_ih   = (const float*)d_in[7];
  const float* w_hh   = (const float*)d_in[8];
  const float* b_ih   = (const float*)d_in[9];
  const float* b_hh   = (const float*)d_in[10];
  const float* fc_w   = (const float*)d_in[11];
  const float* fc_b   = (const float*)d_in[12];
  const float* basis0 = (const float*)d_in[13];
  const float* wcomp0 = (const float*)d_in[14];
  const float* basis1 = (const float*)d_in[15];
  const float* wcomp1 = (const float*)d_in[16];
  const float* basis2 = (const float*)d_in[17];
  const float* wcomp2 = (const float*)d_in[18];

  char* ws = (char*)d_ws;
  u16*   eproj = (u16*)  (ws);               // 10,240,000 B
  float* feats = (float*)(ws + 10240000);    //  7,680,000 B
  float* g1    = (float*)(ws + 17920000);    //  7,680,000 B
  float* g2    = (float*)(ws + 25600000);    //  7,680,000 B
  float* W0t   = (float*)(ws + 33280000);    //    131,072 B
  float* W1t   = (float*)(ws + 33411072);    //    131,072 B
  float* W2t   = (float*)(ws + 33542144);    //     32,768 B

  hipFuncSetAttribute((const void*)rgcn_kernel,
                      hipFuncAttributeMaxDynamicSharedMemorySize, 139264);

  wmat_kernel<<<288, 256, 0, stream>>>(basis0, wcomp0, basis1, wcomp1,
                                       basis2, wcomp2, W0t, W1t, W2t);
  embproj_kernel<<<157, 256, 0, stream>>>(emb, w_ih, b_ih, b_hh, eproj);
  lstm_kernel<<<235, 512, 0, stream>>>(tok, eproj, w_hh, fc_w, fc_b, feats);

  hipMemsetAsync(g1, 0, 30000*64*4, stream);
  rgcn_kernel<<<256, 1024, 8*64*256 + 8192, stream>>>(
      feats, src, dst, rel, enorm, W0t, g1, 480000, 64, 0);
  hipMemsetAsync(g2, 0, 30000*64*4, stream);
  rgcn_kernel<<<256, 1024, 8*64*256 + 8192, stream>>>(
      g1, src, dst, rel, enorm, W1t, g2, 480000, 64, 1);
  hipMemsetAsync(d_out, 0, 30000*16*4, stream);
  rgcn_kernel<<<512, 1024, 8*16*256 + 8192, stream>>>(
      g2, src, dst, rel, enorm, W2t, (float*)d_out, 480000, 16, 1);
}